// Round 1
// 212.733 us; speedup vs baseline: 1.0676x; 1.0676x over previous
//
#include <hip/hip_runtime.h>

// AdaptiveEmbedding round 5:
//   classify (+fused proj->bf16 convert) -> compact bf16 gather -> pure-bf16 MFMA GEMM.
// Round-4 gemm was latency-bound (MfmaUtil 3%, VALUBusy 13%, HBM 23%): every
// m-tile's emb rows were re-gathered (scattered fp32) and re-converted to bf16
// once PER col-tile (16x), proj re-converted per m-tile, 2 barriers per 64-K
// chunk exposing the scatter latency. This round gathers each emb row exactly
// once into a compact bf16 buffer, pre-converts proj to bf16, and the GEMM
// stages both operands with global_load_lds (16B, linear LDS dest, XOR-swizzled
// per-lane global source + matching XOR on ds_read_b128 -- rule "both sides or
// neither"). Tile = 64 tokens x 128 cols (8 col-tiles per m-tile group); m-tile
// groups round-robin across XCDs, the 8 col-tiles of a group stay on one XCD
// (E-block L2 reuse) -- a contiguous XCD slice would dump all K=1024 work on
// XCD0 (56% of FLOPs on 1/8 of the machine).
//
// ws layout (bytes):
//   [0,16)      4x u32 cluster counters (memset)
//   [256, +4*T*4)                lists: (t<<18)|(id-l) per cluster
//   PB = align256(...)           proj bf16: 1024x{1024,256,64,32(c3 zero-pad)}
//   EC = PB + 2,818,048          compact emb bf16, per-cluster, rows cap64ed
// Actual use ~8 MB (worst case ~37 MB if all tokens hit cluster 0).

#define CUT0 20000
#define CUT1 40000
#define CUT2 200000

// proj-bf16 region offsets (elements)
#define PB1 (1024 * 1024)
#define PB2 (PB1 + 1024 * 256)
#define PB3 (PB2 + 1024 * 64)
#define PBEND (PB3 + 1024 * 32)   // 1,409,024 elems = 2,818,048 B

typedef __attribute__((ext_vector_type(8))) short bf16x8;
typedef __attribute__((ext_vector_type(8))) unsigned short u16x8;
typedef __attribute__((ext_vector_type(4))) float f32x4;

__device__ __forceinline__ unsigned short f2bf(float f) {
    unsigned u = __float_as_uint(f);
    u += 0x7FFFu + ((u >> 16) & 1u);   // round-to-nearest-even
    return (unsigned short)(u >> 16);
}

__device__ __forceinline__ u16x8 cvt8(const float* __restrict__ s) {
    float4 a = *(const float4*)s;
    float4 b = *(const float4*)(s + 4);
    return (u16x8){f2bf(a.x), f2bf(a.y), f2bf(a.z), f2bf(a.w),
                   f2bf(b.x), f2bf(b.y), f2bf(b.z), f2bf(b.w)};
}

__device__ __forceinline__ void gl_lds16(const unsigned short* g, unsigned short* s) {
    __builtin_amdgcn_global_load_lds(
        (const __attribute__((address_space(1))) void*)g,
        (__attribute__((address_space(3))) void*)s, 16, 0, 0);
}

// ---- kernel 1: classify tokens + fused proj -> bf16 conversion -------------
__global__ __launch_bounds__(256)
void classify_convert(const int* __restrict__ inp, unsigned* __restrict__ counters,
                      unsigned* __restrict__ lists, int T,
                      const float* __restrict__ proj0, const float* __restrict__ proj1,
                      const float* __restrict__ proj2, const float* __restrict__ proj3,
                      unsigned short* __restrict__ projbf) {
    int t = blockIdx.x * 256 + threadIdx.x;
    int lane = threadIdx.x & 63;
    bool valid = (t < T);
    int id = valid ? inp[t] : 0;
    int c = -1, l = 0;
    if (valid) {
        if (id < CUT0)      { c = 0; l = 0; }
        else if (id < CUT1) { c = 1; l = CUT0; }
        else if (id < CUT2) { c = 2; l = CUT1; }
        else                { c = 3; l = CUT2; }
    }
    #pragma unroll
    for (int i = 0; i < 4; ++i) {
        unsigned long long m = __ballot(c == i);
        if (c == i) {
            int leader = __ffsll(m) - 1;
            unsigned base = 0;
            if (lane == leader) base = atomicAdd(&counters[i], (unsigned)__popcll(m));
            base = __shfl(base, leader);
            unsigned rank = (unsigned)__popcll(m & ((1ull << lane) - 1ull));
            lists[(size_t)i * T + base + rank] = ((unsigned)t << 18) | (unsigned)(id - l);
        }
    }
    // fused proj -> bf16 (grid-stride over 16B output chunks; c3 rows padded to 32)
    const int stride = gridDim.x * 256;
    for (int u = t; u < PBEND / 8; u += stride) {
        int base = u * 8;
        u16x8 o;
        if (base < PB1)       o = cvt8(proj0 + base);
        else if (base < PB2)  o = cvt8(proj1 + (base - PB1));
        else if (base < PB3)  o = cvt8(proj2 + (base - PB2));
        else {
            int rel = base - PB3;
            int row = rel >> 5, col = rel & 31;
            if (col < 16) o = cvt8(proj3 + row * 16 + col);
            else          o = (u16x8){0, 0, 0, 0, 0, 0, 0, 0};
        }
        *(u16x8*)(projbf + base) = o;
    }
}

// ---- kernel 2: gather emb rows once -> compact bf16 per cluster ------------
__global__ __launch_bounds__(256)
void gather_bf16(const float* __restrict__ emb0, const float* __restrict__ emb1,
                 const float* __restrict__ emb2, const float* __restrict__ emb3,
                 const unsigned* __restrict__ lists, const unsigned* __restrict__ counters,
                 int T, unsigned short* __restrict__ ecomp) {
    const int c0 = (int)counters[0], c1 = (int)counters[1];
    const int c2 = (int)counters[2], c3 = (int)counters[3];
    const size_t off1 = (size_t)((c0 + 63) & ~63) * 1024;
    const size_t off2 = off1 + (size_t)((c1 + 63) & ~63) * 256;
    const size_t off3 = off2 + (size_t)((c2 + 63) & ~63) * 64;
    const int n0 = c0 << 7, n1 = c1 << 5, n2 = c2 << 3, n3 = c3 << 2;  // 16B-chunk jobs
    const int total = n0 + n1 + n2 + n3;
    const int stride = gridDim.x * 256;
    for (int u = blockIdx.x * 256 + threadIdx.x; u < total; u += stride) {
        int v = u;
        if (v < n0) {
            int r = v >> 7, j = v & 127;
            unsigned id = lists[r] & 0x3FFFFu;
            *(u16x8*)(ecomp + (size_t)r * 1024 + j * 8) = cvt8(emb0 + (size_t)id * 1024 + j * 8);
        } else if ((v -= n0) < n1) {
            int r = v >> 5, j = v & 31;
            unsigned id = lists[T + r] & 0x3FFFFu;
            *(u16x8*)(ecomp + off1 + (size_t)r * 256 + j * 8) = cvt8(emb1 + (size_t)id * 256 + j * 8);
        } else if ((v -= n1) < n2) {
            int r = v >> 3, j = v & 7;
            unsigned id = lists[2 * T + r] & 0x3FFFFu;
            *(u16x8*)(ecomp + off2 + (size_t)r * 64 + j * 8) = cvt8(emb2 + (size_t)id * 64 + j * 8);
        } else {
            v -= n2;
            int r = v >> 2, j = v & 3;                 // Kp=32, cols 16..31 zero
            unsigned id = lists[3 * T + r] & 0x3FFFFu;
            unsigned short* d = ecomp + off3 + (size_t)r * 32 + j * 8;
            if (j < 2) *(u16x8*)d = cvt8(emb3 + (size_t)id * 16 + j * 8);
            else       *(u16x8*)d = (u16x8){0, 0, 0, 0, 0, 0, 0, 0};
        }
    }
}

// ---- kernel 3: fused persistent bf16 GEMM ----------------------------------
// Tile = 64 rows x 128 cols, 4 waves, K chunked at 64 (32 for cluster 3).
// LDS linear (global_load_lds): swizzle applied to the per-lane GLOBAL source
// and to the ds_read address -- same involution, LDS stays linear.
template<int KP>
__device__ __forceinline__
void tile_gemm(const unsigned short* __restrict__ E, const unsigned short* __restrict__ P,
               const unsigned* __restrict__ list, int count, int mtile, int ntile,
               float* __restrict__ out,
               unsigned short* E_s, unsigned short* P_s, unsigned* pk_s) {
    constexpr int KB  = (KP >= 64) ? 64 : KP;   // 64 or 32
    constexpr int NCH = KP / KB;
    constexpr int KST = KB / 32;                // MFMA k-steps per chunk
    constexpr int CPR = KB / 8;                 // 16B chunks per LDS row (8 or 4)
    constexpr int SWZ = CPR - 1;                // XOR mask (7 or 3)

    const int m0 = mtile * 64;
    const int rows = min(64, count - m0);
    const int py = ntile * 128;
    const int tid = (int)threadIdx.x;
    const int lane = tid & 63;
    const int w  = tid >> 6;
    const int ln = lane & 15;
    const int qd = lane >> 4;

    if (tid < 64) pk_s[tid] = (tid < rows) ? list[m0 + tid] : 0u;  // read after 1st barrier

    f32x4 acc[8];
    #pragma unroll
    for (int ct = 0; ct < 8; ++ct) acc[ct] = (f32x4){0.f, 0.f, 0.f, 0.f};

    const unsigned short* eb = E + (size_t)m0 * KP;   // compact: tile rows contiguous
    const unsigned short* pb = P + (size_t)py * KP;

    for (int ch = 0; ch < NCH; ++ch) {
        const int k0 = ch * KB;
        #pragma unroll
        for (int it = 0; it < (64 * CPR) / 256; ++it) {       // E: 64 x KB bf16
            int i16 = it * 256 + tid;
            int row = i16 / CPR, cc = (i16 % CPR) ^ (row & SWZ);
            gl_lds16(eb + (size_t)row * KP + k0 + cc * 8, E_s + i16 * 8);
        }
        #pragma unroll
        for (int it = 0; it < (128 * CPR) / 256; ++it) {      // P: 128 x KB bf16
            int i16 = it * 256 + tid;
            int row = i16 / CPR, cc = (i16 % CPR) ^ (row & SWZ);
            gl_lds16(pb + (size_t)row * KP + k0 + cc * 8, P_s + i16 * 8);
        }
        __syncthreads();   // drains vmcnt (incl. lds-DMA) before ds_read

        const int ar = w * 16 + ln;
        #pragma unroll
        for (int s = 0; s < KST; ++s) {
            bf16x8 a = *(const bf16x8*)(E_s + ar * KB + (((s * 4 + qd) ^ (ar & SWZ)) * 8));
            #pragma unroll
            for (int ct = 0; ct < 8; ++ct) {
                const int br = ct * 16 + ln;
                bf16x8 b = *(const bf16x8*)(P_s + br * KB + (((s * 4 + qd) ^ (br & SWZ)) * 8));
                acc[ct] = __builtin_amdgcn_mfma_f32_16x16x32_bf16(a, b, acc[ct], 0, 0, 0);
            }
        }
        __syncthreads();
    }

    // C/D layout: col = lane&15, row = (lane>>4)*4 + reg   [m89/m91]
    #pragma unroll
    for (int ct = 0; ct < 8; ++ct) {
        #pragma unroll
        for (int r = 0; r < 4; ++r) {
            int row = w * 16 + qd * 4 + r;
            if (row < rows) {
                int t = (int)(pk_s[row] >> 18);
                out[(size_t)t * 1024 + py + ct * 16 + ln] = acc[ct][r] * 32.0f;
            }
        }
    }
    __syncthreads();   // protect pk_s/LDS before next tile overwrites
}

__global__ __launch_bounds__(256)
void gemm_fused(const unsigned short* __restrict__ ecomp, const unsigned short* __restrict__ projbf,
                const unsigned* __restrict__ lists, const unsigned* __restrict__ counters,
                int T, float* __restrict__ out) {
    __shared__ unsigned short E_s[64 * 64];    //  8 KB
    __shared__ unsigned short P_s[128 * 64];   // 16 KB
    __shared__ unsigned pk_s[64];

    const int c0 = (int)counters[0], c1 = (int)counters[1];
    const int c2 = (int)counters[2], c3 = (int)counters[3];
    const size_t off1 = (size_t)((c0 + 63) & ~63) * 1024;
    const size_t off2 = off1 + (size_t)((c1 + 63) & ~63) * 256;
    const size_t off3 = off2 + (size_t)((c2 + 63) & ~63) * 64;
    const int g0 = (c0 + 63) >> 6;                 // m-tile groups per cluster
    const int g1 = g0 + ((c1 + 63) >> 6);
    const int g2 = g1 + ((c2 + 63) >> 6);
    const int g3 = g2 + ((c3 + 63) >> 6);          // total groups; each = 8 col-tiles

    // XCD map: group (g % 8) -> XCD, 8 col-tiles of a group stay together.
    const int xcd = blockIdx.x & 7;
    const int slot = blockIdx.x >> 3;
    const int nslots = gridDim.x >> 3;

    for (int i = slot; ; i += nslots) {
        const int g = ((i >> 3) << 3) + xcd;       // this XCD's (i>>3)-th group
        if (g >= g3) break;
        const int nt = i & 7;                      // col-tile 0..7
        if (g < g0)      tile_gemm<1024>(ecomp,        projbf,       lists,         c0, g,      nt, out, E_s, P_s, pk_s);
        else if (g < g1) tile_gemm< 256>(ecomp + off1, projbf + PB1, lists + T,     c1, g - g0, nt, out, E_s, P_s, pk_s);
        else if (g < g2) tile_gemm<  64>(ecomp + off2, projbf + PB2, lists + 2 * T, c2, g - g1, nt, out, E_s, P_s, pk_s);
        else             tile_gemm<  32>(ecomp + off3, projbf + PB3, lists + 3 * T, c3, g - g2, nt, out, E_s, P_s, pk_s);
    }
}

extern "C" void kernel_launch(void* const* d_in, const int* in_sizes, int n_in,
                              void* d_out, int out_size, void* d_ws, size_t ws_size,
                              hipStream_t stream) {
    const int*   inp   = (const int*)d_in[0];
    const float* emb0  = (const float*)d_in[1];
    const float* proj0 = (const float*)d_in[2];
    const float* emb1  = (const float*)d_in[3];
    const float* proj1 = (const float*)d_in[4];
    const float* emb2  = (const float*)d_in[5];
    const float* proj2 = (const float*)d_in[6];
    const float* emb3  = (const float*)d_in[7];
    const float* proj3 = (const float*)d_in[8];
    float* out = (float*)d_out;
    const int T = in_sizes[0];   // 16384

    unsigned* counters = (unsigned*)d_ws;
    unsigned* lists    = (unsigned*)((char*)d_ws + 256);
    size_t lists_b = ((size_t)4 * T * 4 + 255) & ~(size_t)255;
    unsigned short* projbf = (unsigned short*)((char*)d_ws + 256 + lists_b);
    unsigned short* ecomp  = projbf + PBEND;

    hipMemsetAsync(counters, 0, 16, stream);
    classify_convert<<<dim3(256), 256, 0, stream>>>(inp, counters, lists, T,
                                                    proj0, proj1, proj2, proj3, projbf);
    gather_bf16<<<dim3(2048), 256, 0, stream>>>(emb0, emb1, emb2, emb3,
                                                lists, counters, T, ecomp);
    // 1536 blocks = 6/CU (LDS 24.8 KB/block); ~2064 tiles, <=2 per block.
    gemm_fused<<<dim3(1536), 256, 0, stream>>>(ecomp, projbf, lists, counters, T, out);
}